// Round 1
// baseline (652.850 us; speedup 1.0000x reference)
//
#include <hip/hip_runtime.h>

#define EMB 128

// ---------- CSR build ----------
__global__ __launch_bounds__(256) void k_count(const int* __restrict__ row,
                                               const int* __restrict__ col,
                                               int* __restrict__ degi,
                                               int* __restrict__ cnt, int E) {
  int k = blockIdx.x * 256 + threadIdx.x;
  if (k < E) {
    atomicAdd(&degi[row[k]], 1);   // out-degree over source (for GCN norm)
    atomicAdd(&cnt[col[k]], 1);    // in-degree over target (for CSR)
  }
}

__global__ __launch_bounds__(256) void k_dinv(const int* __restrict__ degi,
                                              float* __restrict__ dinv, int N) {
  int i = blockIdx.x * 256 + threadIdx.x;
  if (i < N) {
    int d = degi[i];
    float df = (float)(d == 0 ? 1 : d);
    dinv[i] = 1.0f / sqrtf(df);
  }
}

// single-block exclusive scan over cnt -> startp (N up to ~50k, 1024 threads)
__global__ void k_scan(const int* __restrict__ cnt, int* __restrict__ startp, int N) {
  __shared__ int lds[1024];
  __shared__ int carry;
  int tid = threadIdx.x;
  if (tid == 0) carry = 0;
  __syncthreads();
  for (int base = 0; base < N; base += 1024) {
    int i = base + tid;
    int v = (i < N) ? cnt[i] : 0;
    lds[tid] = v;
    __syncthreads();
    for (int off = 1; off < 1024; off <<= 1) {
      int t = (tid >= off) ? lds[tid - off] : 0;
      __syncthreads();
      lds[tid] += t;
      __syncthreads();
    }
    int incl = lds[tid];
    int c = carry;
    if (i < N) startp[i] = c + incl - v;   // exclusive
    int tot = lds[1023];
    __syncthreads();
    if (tid == 0) carry = c + tot;
    __syncthreads();
  }
  if (tid == 0) startp[N] = carry;
}

__global__ __launch_bounds__(256) void k_fill(const int* __restrict__ row,
    const int* __restrict__ col, const int* __restrict__ attr,
    const int* __restrict__ startp, int* __restrict__ cursor,
    const float* __restrict__ dinv, int* __restrict__ cpack,
    float* __restrict__ cnorm, int E) {
  int k = blockIdx.x * 256 + threadIdx.x;
  if (k < E) {
    int r = row[k], c = col[k];
    int pos = startp[c] + atomicAdd(&cursor[c], 1);
    cpack[pos] = r | (attr[k] << 20);        // src < 2^20, bond < 16
    cnorm[pos] = dinv[r] * dinv[c];
  }
}

// ---------- h0 = atom_emb[x] ----------
__global__ __launch_bounds__(256) void k_h0(const int* __restrict__ x,
    const float* __restrict__ atom_emb, float* __restrict__ h, int N) {
  int t = blockIdx.x * 256 + threadIdx.x;
  int i = t >> 5, f = t & 31;                // 32 float4 per row
  if (i < N) {
    float4 v = reinterpret_cast<const float4*>(atom_emb)[x[i] * 32 + f];
    reinterpret_cast<float4*>(h)[i * 32 + f] = v;
  }
}

// ---------- aggregation: one wave per node, no atomics ----------
__global__ __launch_bounds__(256) void k_agg(const float* __restrict__ h,
    const int* __restrict__ startp, const int* __restrict__ cpack,
    const float* __restrict__ cnorm, const float* __restrict__ bond_emb,
    float* __restrict__ agg, int N) {
  int wave = threadIdx.x >> 6, lane = threadIdx.x & 63;
  int node = blockIdx.x * 4 + wave;
  if (node >= N) return;
  int s = startp[node], e = startp[node + 1];
  float accx = 0.f, accy = 0.f;
  int pk = 0; float w = 0.f;
  if (s < e) { pk = cpack[s]; w = cnorm[s]; }
  for (int p = s; p < e; ++p) {
    int pn = (p + 1 < e) ? p + 1 : p;        // prefetch next edge meta
    int pk_n = cpack[pn];
    float w_n = cnorm[pn];
    int src = pk & 0xFFFFF;
    int bd  = pk >> 20;
    float2 hv = *reinterpret_cast<const float2*>(h + (size_t)src * EMB + lane * 2);
    float2 ev = *reinterpret_cast<const float2*>(bond_emb + bd * EMB + lane * 2);
    accx = fmaf(w * hv.x, ev.x, accx);
    accy = fmaf(w * hv.y, ev.y, accy);
    pk = pk_n; w = w_n;
  }
  float2 o; o.x = accx; o.y = accy;
  *reinterpret_cast<float2*>(agg + (size_t)node * EMB + lane * 2) = o;
}

// ---------- h_next = relu(agg @ W + b), f32 register-blocked ----------
__global__ __launch_bounds__(256) void k_gemm(const float* __restrict__ A,
    const float* __restrict__ W, const float* __restrict__ bias,
    float* __restrict__ out, int M) {
  __shared__ float As[128][33];   // +1 pad kills bank conflicts on column reads
  __shared__ float Bs[32][128];
  int tid = threadIdx.x;
  int tx = tid & 15, ty = tid >> 4;
  int r0 = ty * 8, c0 = tx * 8;
  int rowbase = blockIdx.x * 128;
  float acc[8][8];
#pragma unroll
  for (int i = 0; i < 8; ++i)
#pragma unroll
    for (int j = 0; j < 8; ++j) acc[i][j] = 0.f;

  for (int k0 = 0; k0 < 128; k0 += 32) {
    // stage A tile: 128 rows x 32 k
    for (int t = tid; t < 1024; t += 256) {
      int r = t >> 3, f = t & 7;
      int grow = rowbase + r;
      float4 v = make_float4(0.f, 0.f, 0.f, 0.f);
      if (grow < M)
        v = *reinterpret_cast<const float4*>(A + (size_t)grow * EMB + k0 + f * 4);
      As[r][f * 4 + 0] = v.x; As[r][f * 4 + 1] = v.y;
      As[r][f * 4 + 2] = v.z; As[r][f * 4 + 3] = v.w;
    }
    // stage B tile: 32 k x 128 n (contiguous rows of W)
    for (int t = tid; t < 1024; t += 256) {
      int kr = t >> 5, f = t & 31;
      *reinterpret_cast<float4*>(&Bs[kr][f * 4]) =
          *reinterpret_cast<const float4*>(W + (size_t)(k0 + kr) * EMB + f * 4);
    }
    __syncthreads();
#pragma unroll
    for (int k = 0; k < 32; ++k) {
      float a[8], b[8];
#pragma unroll
      for (int i = 0; i < 8; ++i) a[i] = As[r0 + i][k];
      *reinterpret_cast<float4*>(&b[0]) = *reinterpret_cast<float4*>(&Bs[k][c0]);
      *reinterpret_cast<float4*>(&b[4]) = *reinterpret_cast<float4*>(&Bs[k][c0 + 4]);
#pragma unroll
      for (int i = 0; i < 8; ++i)
#pragma unroll
        for (int j = 0; j < 8; ++j)
          acc[i][j] = fmaf(a[i], b[j], acc[i][j]);
    }
    __syncthreads();
  }

  float bl[8];
  *reinterpret_cast<float4*>(&bl[0]) = *reinterpret_cast<const float4*>(bias + c0);
  *reinterpret_cast<float4*>(&bl[4]) = *reinterpret_cast<const float4*>(bias + c0 + 4);
#pragma unroll
  for (int i = 0; i < 8; ++i) {
    int r = rowbase + r0 + i;
    if (r < M) {
      float o[8];
#pragma unroll
      for (int j = 0; j < 8; ++j) o[j] = fmaxf(acc[i][j] + bl[j], 0.f);
      *reinterpret_cast<float4*>(out + (size_t)r * EMB + c0) =
          *reinterpret_cast<float4*>(&o[0]);
      *reinterpret_cast<float4*>(out + (size_t)r * EMB + c0 + 4) =
          *reinterpret_cast<float4*>(&o[4]);
    }
  }
}

extern "C" void kernel_launch(void* const* d_in, const int* in_sizes, int n_in,
                              void* d_out, int out_size, void* d_ws, size_t ws_size,
                              hipStream_t stream) {
  const int*   x        = (const int*)d_in[0];
  const int*   eidx     = (const int*)d_in[1];
  const int*   eattr    = (const int*)d_in[2];
  const float* atom_emb = (const float*)d_in[3];
  const float* bond_emb = (const float*)d_in[4];
  const float* lin_W    = (const float*)d_in[5];
  const float* lin_b    = (const float*)d_in[6];
  float* out = (float*)d_out;

  const int N = in_sizes[0];
  const int E = in_sizes[1] / 2;
  const int L = in_sizes[5] / (EMB * EMB);
  const int* row = eidx;
  const int* col = eidx + E;

  char* ws = (char*)d_ws;
  size_t off = 0;
  auto alloc = [&](size_t bytes) {
    char* p = ws + off;
    off += (bytes + 255) & ~(size_t)255;
    return p;
  };
  float* agg    = (float*)alloc((size_t)N * EMB * 4);
  float* hbuf   = (float*)alloc((size_t)N * EMB * 4);
  int*   degi   = (int*)alloc((size_t)N * 4);
  int*   cnt    = (int*)alloc((size_t)N * 4);
  int*   cursor = (int*)alloc((size_t)N * 4);
  int*   startp = (int*)alloc((size_t)(N + 1) * 4);
  float* dinv   = (float*)alloc((size_t)N * 4);
  int*   cpack  = (int*)alloc((size_t)E * 4);
  float* cnorm  = (float*)alloc((size_t)E * 4);
  (void)ws_size; (void)n_in; (void)out_size;

  hipMemsetAsync(degi, 0, (size_t)N * 4, stream);
  hipMemsetAsync(cnt, 0, (size_t)N * 4, stream);
  hipMemsetAsync(cursor, 0, (size_t)N * 4, stream);

  int eb = (E + 255) / 256;
  int nb = (N + 255) / 256;
  k_count<<<eb, 256, 0, stream>>>(row, col, degi, cnt, E);
  k_dinv<<<nb, 256, 0, stream>>>(degi, dinv, N);
  k_scan<<<1, 1024, 0, stream>>>(cnt, startp, N);
  k_fill<<<eb, 256, 0, stream>>>(row, col, eattr, startp, cursor, dinv, cpack, cnorm, E);
  k_h0<<<((size_t)N * 32 + 255) / 256, 256, 0, stream>>>(x, atom_emb, hbuf, N);

  float* hcur = hbuf;
  for (int l = 0; l < L; ++l) {
    k_agg<<<(N + 3) / 4, 256, 0, stream>>>(hcur, startp, cpack, cnorm, bond_emb, agg, N);
    float* hnext;
    if (l == L - 1) hnext = out;
    else hnext = (hcur == hbuf) ? out : hbuf;
    k_gemm<<<(N + 127) / 128, 256, 0, stream>>>(agg, lin_W + (size_t)l * EMB * EMB,
                                                lin_b + (size_t)l * EMB, hnext, N);
    hcur = hnext;
  }
}

// Round 2
// 521.584 us; speedup vs baseline: 1.2517x; 1.2517x over previous
//
#include <hip/hip_runtime.h>

#define EMB 128

// ---------- CSR build ----------
__global__ __launch_bounds__(256) void k_count(const int* __restrict__ row,
                                               const int* __restrict__ col,
                                               int* __restrict__ degi,
                                               int* __restrict__ cnt, int E) {
  int k = blockIdx.x * 256 + threadIdx.x;
  if (k < E) {
    atomicAdd(&degi[row[k]], 1);   // out-degree over source (for GCN norm)
    atomicAdd(&cnt[col[k]], 1);    // in-degree over target (for CSR)
  }
}

__global__ __launch_bounds__(256) void k_dinv(const int* __restrict__ degi,
                                              float* __restrict__ dinv, int N) {
  int i = blockIdx.x * 256 + threadIdx.x;
  if (i < N) {
    int d = degi[i];
    float df = (float)(d == 0 ? 1 : d);
    dinv[i] = 1.0f / sqrtf(df);
  }
}

// ---------- multi-block exclusive scan: local -> partials -> add ----------
__global__ __launch_bounds__(256) void k_scan_local(const int* __restrict__ cnt,
    int* __restrict__ startp, int* __restrict__ partial, int N) {
  __shared__ int lds[256];
  int tid = threadIdx.x;
  int i = blockIdx.x * 256 + tid;
  int v = (i < N) ? cnt[i] : 0;
  lds[tid] = v;
  __syncthreads();
#pragma unroll
  for (int off = 1; off < 256; off <<= 1) {
    int t = (tid >= off) ? lds[tid - off] : 0;
    __syncthreads();
    lds[tid] += t;
    __syncthreads();
  }
  if (i < N) startp[i] = lds[tid] - v;      // exclusive within block
  if (tid == 255) partial[blockIdx.x] = lds[255];
}

__global__ void k_scan_part(int* __restrict__ partial, int nb) {
  __shared__ int lds[1024];
  int tid = threadIdx.x;
  int v = (tid < nb) ? partial[tid] : 0;
  lds[tid] = v;
  __syncthreads();
  for (int off = 1; off < 1024; off <<= 1) {
    int t = (tid >= off) ? lds[tid - off] : 0;
    __syncthreads();
    lds[tid] += t;
    __syncthreads();
  }
  if (tid < nb) partial[tid] = lds[tid] - v;   // exclusive block offsets
}

__global__ __launch_bounds__(256) void k_scan_add(int* __restrict__ startp,
    const int* __restrict__ partial, int N, int E) {
  int i = blockIdx.x * 256 + threadIdx.x;
  if (i < N) startp[i] += partial[blockIdx.x];
  if (i == 0) startp[N] = E;                   // total is E by construction
}

__global__ __launch_bounds__(256) void k_fill(const int* __restrict__ row,
    const int* __restrict__ col, const int* __restrict__ attr,
    const int* __restrict__ startp, int* __restrict__ cursor,
    const float* __restrict__ dinv, int2* __restrict__ emeta, int E) {
  int k = blockIdx.x * 256 + threadIdx.x;
  if (k < E) {
    int r = row[k], c = col[k];
    int pos = startp[c] + atomicAdd(&cursor[c], 1);
    int2 m;
    m.x = r | (attr[k] << 20);                 // src < 2^20, bond < 16
    m.y = __float_as_int(dinv[r] * dinv[c]);
    emeta[pos] = m;
  }
}

// ---------- h0 = atom_emb[x] ----------
__global__ __launch_bounds__(256) void k_h0(const int* __restrict__ x,
    const float* __restrict__ atom_emb, float* __restrict__ h, int N) {
  int t = blockIdx.x * 256 + threadIdx.x;
  int i = t >> 5, f = t & 31;                  // 32 float4 per row
  if (i < N) {
    float4 v = reinterpret_cast<const float4*>(atom_emb)[x[i] * 32 + f];
    reinterpret_cast<float4*>(h)[i * 32 + f] = v;
  }
}

// ---------- aggregation: one wave per node, 4x-unrolled gather ----------
__global__ __launch_bounds__(256) void k_agg(const float* __restrict__ h,
    const int* __restrict__ startp, const int2* __restrict__ emeta,
    const float* __restrict__ bond_emb, float* __restrict__ agg, int N, int BV) {
  __shared__ float eb_lds[16 * EMB];           // bond table, 8 KB
  if (BV <= 16) {
    for (int t = threadIdx.x; t < BV * (EMB / 4); t += 256)
      reinterpret_cast<float4*>(eb_lds)[t] =
          reinterpret_cast<const float4*>(bond_emb)[t];
  }
  __syncthreads();

  int wave = threadIdx.x >> 6, lane = threadIdx.x & 63;
  int node = blockIdx.x * 4 + wave;
  if (node >= N) return;
  int s = startp[node], e = startp[node + 1];
  float accx = 0.f, accy = 0.f;
  int p = s;
  for (; p + 4 <= e; p += 4) {
    int2 m0 = emeta[p + 0];
    int2 m1 = emeta[p + 1];
    int2 m2 = emeta[p + 2];
    int2 m3 = emeta[p + 3];
    const float2* h0 = reinterpret_cast<const float2*>(h + (size_t)(m0.x & 0xFFFFF) * EMB) + lane;
    const float2* h1 = reinterpret_cast<const float2*>(h + (size_t)(m1.x & 0xFFFFF) * EMB) + lane;
    const float2* h2 = reinterpret_cast<const float2*>(h + (size_t)(m2.x & 0xFFFFF) * EMB) + lane;
    const float2* h3 = reinterpret_cast<const float2*>(h + (size_t)(m3.x & 0xFFFFF) * EMB) + lane;
    float2 a0 = *h0, a1 = *h1, a2 = *h2, a3 = *h3;   // 4 outstanding gathers
    float2 e0 = *(reinterpret_cast<const float2*>(eb_lds + (m0.x >> 20) * EMB) + lane);
    float2 e1 = *(reinterpret_cast<const float2*>(eb_lds + (m1.x >> 20) * EMB) + lane);
    float2 e2 = *(reinterpret_cast<const float2*>(eb_lds + (m2.x >> 20) * EMB) + lane);
    float2 e3 = *(reinterpret_cast<const float2*>(eb_lds + (m3.x >> 20) * EMB) + lane);
    float w0 = __int_as_float(m0.y), w1 = __int_as_float(m1.y);
    float w2 = __int_as_float(m2.y), w3 = __int_as_float(m3.y);
    accx = fmaf(w0 * a0.x, e0.x, accx);
    accy = fmaf(w0 * a0.y, e0.y, accy);
    accx = fmaf(w1 * a1.x, e1.x, accx);
    accy = fmaf(w1 * a1.y, e1.y, accy);
    accx = fmaf(w2 * a2.x, e2.x, accx);
    accy = fmaf(w2 * a2.y, e2.y, accy);
    accx = fmaf(w3 * a3.x, e3.x, accx);
    accy = fmaf(w3 * a3.y, e3.y, accy);
  }
  for (; p < e; ++p) {
    int2 m = emeta[p];
    float2 hv = *(reinterpret_cast<const float2*>(h + (size_t)(m.x & 0xFFFFF) * EMB) + lane);
    float2 ev = *(reinterpret_cast<const float2*>(eb_lds + (m.x >> 20) * EMB) + lane);
    float w = __int_as_float(m.y);
    accx = fmaf(w * hv.x, ev.x, accx);
    accy = fmaf(w * hv.y, ev.y, accy);
  }
  float2 o; o.x = accx; o.y = accy;
  *reinterpret_cast<float2*>(agg + (size_t)node * EMB + lane * 2) = o;
}

// ---------- h_next = relu(agg @ W + b), f32 register-blocked ----------
__global__ __launch_bounds__(256) void k_gemm(const float* __restrict__ A,
    const float* __restrict__ W, const float* __restrict__ bias,
    float* __restrict__ out, int M) {
  __shared__ float As[128][33];   // +1 pad kills bank conflicts on column reads
  __shared__ float Bs[32][128];
  int tid = threadIdx.x;
  int tx = tid & 15, ty = tid >> 4;
  int r0 = ty * 8, c0 = tx * 8;
  int rowbase = blockIdx.x * 128;
  float acc[8][8];
#pragma unroll
  for (int i = 0; i < 8; ++i)
#pragma unroll
    for (int j = 0; j < 8; ++j) acc[i][j] = 0.f;

  for (int k0 = 0; k0 < 128; k0 += 32) {
    for (int t = tid; t < 1024; t += 256) {
      int r = t >> 3, f = t & 7;
      int grow = rowbase + r;
      float4 v = make_float4(0.f, 0.f, 0.f, 0.f);
      if (grow < M)
        v = *reinterpret_cast<const float4*>(A + (size_t)grow * EMB + k0 + f * 4);
      As[r][f * 4 + 0] = v.x; As[r][f * 4 + 1] = v.y;
      As[r][f * 4 + 2] = v.z; As[r][f * 4 + 3] = v.w;
    }
    for (int t = tid; t < 1024; t += 256) {
      int kr = t >> 5, f = t & 31;
      *reinterpret_cast<float4*>(&Bs[kr][f * 4]) =
          *reinterpret_cast<const float4*>(W + (size_t)(k0 + kr) * EMB + f * 4);
    }
    __syncthreads();
#pragma unroll
    for (int k = 0; k < 32; ++k) {
      float a[8], b[8];
#pragma unroll
      for (int i = 0; i < 8; ++i) a[i] = As[r0 + i][k];
      *reinterpret_cast<float4*>(&b[0]) = *reinterpret_cast<float4*>(&Bs[k][c0]);
      *reinterpret_cast<float4*>(&b[4]) = *reinterpret_cast<float4*>(&Bs[k][c0 + 4]);
#pragma unroll
      for (int i = 0; i < 8; ++i)
#pragma unroll
        for (int j = 0; j < 8; ++j)
          acc[i][j] = fmaf(a[i], b[j], acc[i][j]);
    }
    __syncthreads();
  }

  float bl[8];
  *reinterpret_cast<float4*>(&bl[0]) = *reinterpret_cast<const float4*>(bias + c0);
  *reinterpret_cast<float4*>(&bl[4]) = *reinterpret_cast<const float4*>(bias + c0 + 4);
#pragma unroll
  for (int i = 0; i < 8; ++i) {
    int r = rowbase + r0 + i;
    if (r < M) {
      float o[8];
#pragma unroll
      for (int j = 0; j < 8; ++j) o[j] = fmaxf(acc[i][j] + bl[j], 0.f);
      *reinterpret_cast<float4*>(out + (size_t)r * EMB + c0) =
          *reinterpret_cast<float4*>(&o[0]);
      *reinterpret_cast<float4*>(out + (size_t)r * EMB + c0 + 4) =
          *reinterpret_cast<float4*>(&o[4]);
    }
  }
}

extern "C" void kernel_launch(void* const* d_in, const int* in_sizes, int n_in,
                              void* d_out, int out_size, void* d_ws, size_t ws_size,
                              hipStream_t stream) {
  const int*   x        = (const int*)d_in[0];
  const int*   eidx     = (const int*)d_in[1];
  const int*   eattr    = (const int*)d_in[2];
  const float* atom_emb = (const float*)d_in[3];
  const float* bond_emb = (const float*)d_in[4];
  const float* lin_W    = (const float*)d_in[5];
  const float* lin_b    = (const float*)d_in[6];
  float* out = (float*)d_out;

  const int N = in_sizes[0];
  const int E = in_sizes[1] / 2;
  const int L = in_sizes[5] / (EMB * EMB);
  const int BV = in_sizes[4] / EMB;
  const int* row = eidx;
  const int* col = eidx + E;

  char* ws = (char*)d_ws;
  size_t off = 0;
  auto alloc = [&](size_t bytes) {
    char* p = ws + off;
    off += (bytes + 255) & ~(size_t)255;
    return p;
  };
  float* agg     = (float*)alloc((size_t)N * EMB * 4);
  float* hbuf    = (float*)alloc((size_t)N * EMB * 4);
  int*   degi    = (int*)alloc((size_t)N * 4);
  int*   cnt     = (int*)alloc((size_t)N * 4);
  int*   cursor  = (int*)alloc((size_t)N * 4);
  int*   startp  = (int*)alloc((size_t)(N + 1) * 4);
  float* dinv    = (float*)alloc((size_t)N * 4);
  int*   partial = (int*)alloc((size_t)1024 * 4);
  int2*  emeta   = (int2*)alloc((size_t)E * 8);
  (void)ws_size; (void)n_in; (void)out_size;

  hipMemsetAsync(degi, 0, (size_t)N * 4, stream);
  hipMemsetAsync(cnt, 0, (size_t)N * 4, stream);
  hipMemsetAsync(cursor, 0, (size_t)N * 4, stream);

  int eb = (E + 255) / 256;
  int nb = (N + 255) / 256;
  k_count<<<eb, 256, 0, stream>>>(row, col, degi, cnt, E);
  k_dinv<<<nb, 256, 0, stream>>>(degi, dinv, N);
  k_scan_local<<<nb, 256, 0, stream>>>(cnt, startp, partial, N);
  k_scan_part<<<1, 1024, 0, stream>>>(partial, nb);
  k_scan_add<<<nb, 256, 0, stream>>>(startp, partial, N, E);
  k_fill<<<eb, 256, 0, stream>>>(row, col, eattr, startp, cursor, dinv, emeta, E);
  k_h0<<<((size_t)N * 32 + 255) / 256, 256, 0, stream>>>(x, atom_emb, hbuf, N);

  float* hcur = hbuf;
  for (int l = 0; l < L; ++l) {
    k_agg<<<(N + 3) / 4, 256, 0, stream>>>(hcur, startp, emeta, bond_emb, agg, N, BV);
    float* hnext;
    if (l == L - 1) hnext = out;
    else hnext = (hcur == hbuf) ? out : hbuf;
    k_gemm<<<(N + 127) / 128, 256, 0, stream>>>(agg, lin_W + (size_t)l * EMB * EMB,
                                                lin_b + (size_t)l * EMB, hnext, N);
    hcur = hnext;
  }
}

// Round 3
// 467.383 us; speedup vs baseline: 1.3968x; 1.1160x over previous
//
#include <hip/hip_runtime.h>

#define EMB 128
#define PAD 16   // ints per counter slot (64B line)

typedef __attribute__((ext_vector_type(8))) short bf16x8;
typedef __attribute__((ext_vector_type(4))) float f32x4;

__device__ inline unsigned short f2bf(float f) {
  unsigned u = __float_as_uint(f);
  return (unsigned short)((u + 0x7FFF + ((u >> 16) & 1)) >> 16);   // RNE
}
__device__ inline float bf2f(unsigned short s) {
  return __uint_as_float(((unsigned)s) << 16);
}

// ---------- CSR build ----------
__global__ __launch_bounds__(256) void k_count(const int* __restrict__ row,
    const int* __restrict__ col, int* __restrict__ degi,
    int* __restrict__ cnt, int* __restrict__ ord, int E) {
  int k = blockIdx.x * 256 + threadIdx.x;
  if (k < E) {
    atomicAdd(&degi[row[k] * PAD], 1);              // out-degree (GCN norm)
    ord[k] = atomicAdd(&cnt[col[k] * PAD], 1);      // in-degree + arrival order
  }
}

__global__ __launch_bounds__(256) void k_dinv(const int* __restrict__ degi,
                                              float* __restrict__ dinv, int N) {
  int i = blockIdx.x * 256 + threadIdx.x;
  if (i < N) {
    int d = degi[i * PAD];
    float df = (float)(d == 0 ? 1 : d);
    dinv[i] = 1.0f / sqrtf(df);
  }
}

// ---------- multi-block exclusive scan ----------
__global__ __launch_bounds__(256) void k_scan_local(const int* __restrict__ cnt,
    int* __restrict__ startp, int* __restrict__ partial, int N) {
  __shared__ int lds[256];
  int tid = threadIdx.x;
  int i = blockIdx.x * 256 + tid;
  int v = (i < N) ? cnt[i * PAD] : 0;
  lds[tid] = v;
  __syncthreads();
#pragma unroll
  for (int off = 1; off < 256; off <<= 1) {
    int t = (tid >= off) ? lds[tid - off] : 0;
    __syncthreads();
    lds[tid] += t;
    __syncthreads();
  }
  if (i < N) startp[i] = lds[tid] - v;
  if (tid == 255) partial[blockIdx.x] = lds[255];
}

__global__ void k_scan_part(int* __restrict__ partial, int nb) {
  __shared__ int lds[1024];
  int tid = threadIdx.x;
  int v = (tid < nb) ? partial[tid] : 0;
  lds[tid] = v;
  __syncthreads();
  for (int off = 1; off < 1024; off <<= 1) {
    int t = (tid >= off) ? lds[tid - off] : 0;
    __syncthreads();
    lds[tid] += t;
    __syncthreads();
  }
  if (tid < nb) partial[tid] = lds[tid] - v;
}

__global__ __launch_bounds__(256) void k_scan_add(int* __restrict__ startp,
    const int* __restrict__ partial, int N, int E) {
  int i = blockIdx.x * 256 + threadIdx.x;
  if (i < N) startp[i] += partial[blockIdx.x];
  if (i == 0) startp[N] = E;
}

__global__ __launch_bounds__(256) void k_fill(const int* __restrict__ row,
    const int* __restrict__ col, const int* __restrict__ attr,
    const int* __restrict__ startp, const int* __restrict__ ord,
    const float* __restrict__ dinv, int2* __restrict__ emeta, int E) {
  int k = blockIdx.x * 256 + threadIdx.x;
  if (k < E) {
    int r = row[k], c = col[k];
    int pos = startp[c] + ord[k];
    int2 m;
    m.x = r | (attr[k] << 20);
    m.y = __float_as_int(dinv[r] * dinv[c]);
    emeta[pos] = m;
  }
}

// ---------- h0 = atom_emb[x] ----------
__global__ __launch_bounds__(256) void k_h0(const int* __restrict__ x,
    const float* __restrict__ atom_emb, float* __restrict__ h, int N) {
  int t = blockIdx.x * 256 + threadIdx.x;
  int i = t >> 5, f = t & 31;
  if (i < N) {
    float4 v = reinterpret_cast<const float4*>(atom_emb)[x[i] * 32 + f];
    reinterpret_cast<float4*>(h)[i * 32 + f] = v;
  }
}

// ---------- W split: Wt[l][ 0..127 ][k]=hi, Wt[l][128..255][k]=lo (col-major) ----
__global__ __launch_bounds__(256) void k_wsplit(const float* __restrict__ W,
    unsigned short* __restrict__ Wt, int total) {
  int t = blockIdx.x * 256 + threadIdx.x;   // t = (l*128 + k)*128 + n
  if (t >= total) return;
  int n = t & 127, k = (t >> 7) & 127, l = t >> 14;
  float v = W[t];
  unsigned short hi = f2bf(v);
  unsigned short lo = f2bf(v - bf2f(hi));
  size_t base = (size_t)l * 256 * EMB;
  Wt[base + (size_t)n * EMB + k] = hi;
  Wt[base + (size_t)(128 + n) * EMB + k] = lo;
}

// ---------- aggregation: one wave per node; writes split-bf16 agg ----------
__global__ __launch_bounds__(256) void k_agg(const float* __restrict__ h,
    const int* __restrict__ startp, const int2* __restrict__ emeta,
    const float* __restrict__ bond_emb, unsigned short* __restrict__ Ahi,
    unsigned short* __restrict__ Alo, int N, int BV) {
  __shared__ float eb_lds[16 * EMB];
  if (BV <= 16) {
    for (int t = threadIdx.x; t < BV * (EMB / 4); t += 256)
      reinterpret_cast<float4*>(eb_lds)[t] =
          reinterpret_cast<const float4*>(bond_emb)[t];
  }
  __syncthreads();

  int wave = threadIdx.x >> 6, lane = threadIdx.x & 63;
  int node = blockIdx.x * 4 + wave;
  if (node >= N) return;
  int s = startp[node], e = startp[node + 1];
  float accx = 0.f, accy = 0.f;
  int p = s;
  for (; p + 4 <= e; p += 4) {
    int2 m0 = emeta[p + 0];
    int2 m1 = emeta[p + 1];
    int2 m2 = emeta[p + 2];
    int2 m3 = emeta[p + 3];
    float2 a0 = *(reinterpret_cast<const float2*>(h + (size_t)(m0.x & 0xFFFFF) * EMB) + lane);
    float2 a1 = *(reinterpret_cast<const float2*>(h + (size_t)(m1.x & 0xFFFFF) * EMB) + lane);
    float2 a2 = *(reinterpret_cast<const float2*>(h + (size_t)(m2.x & 0xFFFFF) * EMB) + lane);
    float2 a3 = *(reinterpret_cast<const float2*>(h + (size_t)(m3.x & 0xFFFFF) * EMB) + lane);
    float2 e0 = *(reinterpret_cast<const float2*>(eb_lds + (m0.x >> 20) * EMB) + lane);
    float2 e1 = *(reinterpret_cast<const float2*>(eb_lds + (m1.x >> 20) * EMB) + lane);
    float2 e2 = *(reinterpret_cast<const float2*>(eb_lds + (m2.x >> 20) * EMB) + lane);
    float2 e3 = *(reinterpret_cast<const float2*>(eb_lds + (m3.x >> 20) * EMB) + lane);
    float w0 = __int_as_float(m0.y), w1 = __int_as_float(m1.y);
    float w2 = __int_as_float(m2.y), w3 = __int_as_float(m3.y);
    accx = fmaf(w0 * a0.x, e0.x, accx);
    accy = fmaf(w0 * a0.y, e0.y, accy);
    accx = fmaf(w1 * a1.x, e1.x, accx);
    accy = fmaf(w1 * a1.y, e1.y, accy);
    accx = fmaf(w2 * a2.x, e2.x, accx);
    accy = fmaf(w2 * a2.y, e2.y, accy);
    accx = fmaf(w3 * a3.x, e3.x, accx);
    accy = fmaf(w3 * a3.y, e3.y, accy);
  }
  for (; p < e; ++p) {
    int2 m = emeta[p];
    float2 hv = *(reinterpret_cast<const float2*>(h + (size_t)(m.x & 0xFFFFF) * EMB) + lane);
    float2 ev = *(reinterpret_cast<const float2*>(eb_lds + (m.x >> 20) * EMB) + lane);
    float w = __int_as_float(m.y);
    accx = fmaf(w * hv.x, ev.x, accx);
    accy = fmaf(w * hv.y, ev.y, accy);
  }
  unsigned short hx = f2bf(accx), hy = f2bf(accy);
  unsigned short lx = f2bf(accx - bf2f(hx)), ly = f2bf(accy - bf2f(hy));
  ushort2 hv2; hv2.x = hx; hv2.y = hy;
  ushort2 lv2; lv2.x = lx; lv2.y = ly;
  reinterpret_cast<ushort2*>(Ahi + (size_t)node * EMB)[lane] = hv2;
  reinterpret_cast<ushort2*>(Alo + (size_t)node * EMB)[lane] = lv2;
}

// ---------- h_next = relu(split_bf16(agg) @ W + b) via MFMA ----------
__global__ __launch_bounds__(256) void k_gemm(const unsigned short* __restrict__ Ahi,
    const unsigned short* __restrict__ Alo, const unsigned short* __restrict__ Wt,
    const float* __restrict__ bias, float* __restrict__ outp, int M) {
  int wave = threadIdx.x >> 6, lane = threadIdx.x & 63;
  int lr = lane & 15, lg = lane >> 4;
  int rowbase = blockIdx.x * 128 + wave * 32;
  f32x4 acc[2][8];
#pragma unroll
  for (int m = 0; m < 2; ++m)
#pragma unroll
    for (int n = 0; n < 8; ++n) acc[m][n] = (f32x4){0.f, 0.f, 0.f, 0.f};

#pragma unroll
  for (int kb = 0; kb < 4; ++kb) {
    int koff = kb * 32 + lg * 8;
    bf16x8 ah[2], al[2];
#pragma unroll
    for (int m = 0; m < 2; ++m) {
      int r = rowbase + m * 16 + lr;
      if (r >= M) r = M - 1;                 // clamp; stores are guarded
      ah[m] = *reinterpret_cast<const bf16x8*>(Ahi + (size_t)r * EMB + koff);
      al[m] = *reinterpret_cast<const bf16x8*>(Alo + (size_t)r * EMB + koff);
    }
#pragma unroll
    for (int n = 0; n < 8; ++n) {
      const unsigned short* wp = Wt + (size_t)(n * 16 + lr) * EMB + koff;
      bf16x8 bh = *reinterpret_cast<const bf16x8*>(wp);
      bf16x8 bl = *reinterpret_cast<const bf16x8*>(wp + 128 * EMB);
#pragma unroll
      for (int m = 0; m < 2; ++m) {
        acc[m][n] = __builtin_amdgcn_mfma_f32_16x16x32_bf16(ah[m], bh, acc[m][n], 0, 0, 0);
        acc[m][n] = __builtin_amdgcn_mfma_f32_16x16x32_bf16(al[m], bh, acc[m][n], 0, 0, 0);
        acc[m][n] = __builtin_amdgcn_mfma_f32_16x16x32_bf16(ah[m], bl, acc[m][n], 0, 0, 0);
      }
    }
  }

#pragma unroll
  for (int n = 0; n < 8; ++n) {
    float bv = bias[n * 16 + lr];
#pragma unroll
    for (int m = 0; m < 2; ++m) {
#pragma unroll
      for (int r4 = 0; r4 < 4; ++r4) {
        int row = rowbase + m * 16 + lg * 4 + r4;
        if (row < M)
          outp[(size_t)row * EMB + n * 16 + lr] = fmaxf(acc[m][n][r4] + bv, 0.f);
      }
    }
  }
}

extern "C" void kernel_launch(void* const* d_in, const int* in_sizes, int n_in,
                              void* d_out, int out_size, void* d_ws, size_t ws_size,
                              hipStream_t stream) {
  const int*   x        = (const int*)d_in[0];
  const int*   eidx     = (const int*)d_in[1];
  const int*   eattr    = (const int*)d_in[2];
  const float* atom_emb = (const float*)d_in[3];
  const float* bond_emb = (const float*)d_in[4];
  const float* lin_W    = (const float*)d_in[5];
  const float* lin_b    = (const float*)d_in[6];
  float* out = (float*)d_out;

  const int N = in_sizes[0];
  const int E = in_sizes[1] / 2;
  const int L = in_sizes[5] / (EMB * EMB);
  const int BV = in_sizes[4] / EMB;
  const int* row = eidx;
  const int* col = eidx + E;

  char* ws = (char*)d_ws;
  size_t off = 0;
  auto alloc = [&](size_t bytes) {
    char* p = ws + off;
    off += (bytes + 255) & ~(size_t)255;
    return p;
  };
  float*          hbuf    = (float*)alloc((size_t)N * EMB * 4);
  unsigned short* Ahi     = (unsigned short*)alloc((size_t)N * EMB * 2);
  unsigned short* Alo     = (unsigned short*)alloc((size_t)N * EMB * 2);
  unsigned short* Wt      = (unsigned short*)alloc((size_t)L * 256 * EMB * 2);
  int*            degi    = (int*)alloc((size_t)N * PAD * 4);
  int*            cnt     = (int*)alloc((size_t)N * PAD * 4);
  int*            startp  = (int*)alloc((size_t)(N + 1) * 4);
  float*          dinv    = (float*)alloc((size_t)N * 4);
  int*            partial = (int*)alloc((size_t)1024 * 4);
  int*            ord     = (int*)alloc((size_t)E * 4);
  int2*           emeta   = (int2*)alloc((size_t)E * 8);
  (void)ws_size; (void)n_in; (void)out_size;

  hipMemsetAsync(degi, 0, (size_t)N * PAD * 4, stream);
  hipMemsetAsync(cnt, 0, (size_t)N * PAD * 4, stream);

  int eb = (E + 255) / 256;
  int nb = (N + 255) / 256;
  k_count<<<eb, 256, 0, stream>>>(row, col, degi, cnt, ord, E);
  k_dinv<<<nb, 256, 0, stream>>>(degi, dinv, N);
  k_scan_local<<<nb, 256, 0, stream>>>(cnt, startp, partial, N);
  k_scan_part<<<1, 1024, 0, stream>>>(partial, nb);
  k_scan_add<<<nb, 256, 0, stream>>>(startp, partial, N, E);
  k_fill<<<eb, 256, 0, stream>>>(row, col, eattr, startp, ord, dinv, emeta, E);
  k_h0<<<((size_t)N * 32 + 255) / 256, 256, 0, stream>>>(x, atom_emb, hbuf, N);
  int wtot = L * EMB * EMB;
  k_wsplit<<<(wtot + 255) / 256, 256, 0, stream>>>(lin_W, Wt, wtot);

  float* hcur = hbuf;
  for (int l = 0; l < L; ++l) {
    k_agg<<<(N + 3) / 4, 256, 0, stream>>>(hcur, startp, emeta, bond_emb, Ahi, Alo, N, BV);
    float* hnext;
    if (l == L - 1) hnext = out;
    else hnext = (hcur == hbuf) ? out : hbuf;
    k_gemm<<<(N + 127) / 128, 256, 0, stream>>>(Ahi, Alo, Wt + (size_t)l * 256 * EMB,
                                                lin_b + (size_t)l * EMB, hnext, N);
    hcur = hnext;
  }
}